// Round 11
// baseline (724.660 us; speedup 1.0000x reference)
//
#include <hip/hip_runtime.h>
#include <hip/hip_bf16.h>

#define NT 100000
#define NT_PAD 100032     // 1563 * 64
#define BQ 1024
#define DD 256
#define NGROUPS 128
#define NTILES 1563       // ceil(100000/64)
#define TBLOCKS (NT_PAD / 4)   // 25008 blocks for t rows in normalize_all

typedef __attribute__((ext_vector_type(8))) short bf16x8;
typedef __attribute__((ext_vector_type(4))) float f32x4;

__device__ __forceinline__ unsigned short f2bf(float x) {
    union { float f; unsigned u; } a; a.f = x;
    unsigned r = (a.u + 0x7fffu + ((a.u >> 16) & 1u)) >> 16;  // RNE
    return (unsigned short)r;
}

// async global->LDS DMA, 16B per lane; lds dest must be wave-uniform base
__device__ __forceinline__ void gl_lds16(const void* g, void* l) {
    __builtin_amdgcn_global_load_lds(
        (const __attribute__((address_space(1))) unsigned int*)g,
        (__attribute__((address_space(3))) unsigned int*)l, 16, 0, 0);
}

// ---- normalize one fp32 row (256 elems) -> packed bf16 uint2 for this lane ----
__device__ __forceinline__ uint2 norm_row(const float* __restrict__ src, int lane) {
    float4 v = ((const float4*)src)[lane];
    float s = v.x * v.x + v.y * v.y + v.z * v.z + v.w * v.w;
    #pragma unroll
    for (int m = 1; m < 64; m <<= 1) s += __shfl_xor(s, m, 64);
    float sc = rsqrtf(fmaxf(s, 1e-24f));
    uint2 pk;
    pk.x = (unsigned)f2bf(v.x * sc) | ((unsigned)f2bf(v.y * sc) << 16);
    pk.y = (unsigned)f2bf(v.z * sc) | ((unsigned)f2bf(v.w * sc) << 16);
    return pk;
}

// ---- fused: zero accumulators + normalize q + (optionally) normalize t ----
template<bool DO_T>
__global__ void normalize_all(const float* __restrict__ q, const float* __restrict__ t,
                              unsigned short* __restrict__ qn, unsigned short* __restrict__ tn,
                              float* __restrict__ accz) {
    int lane = threadIdx.x & 63, wid = threadIdx.x >> 6;
    int b = blockIdx.x;
    if (b < 8) accz[b * 256 + threadIdx.x] = 0.f;   // acc_e(1024) + acc_ed(1024)

    if (DO_T && b < TBLOCKS) {
        int row = b * 4 + wid;                      // covers exactly NT_PAD rows
        uint2 pk; pk.x = 0u; pk.y = 0u;
        if (row < NT) pk = norm_row(t + (size_t)row * DD, lane);
        *(uint2*)&tn[(size_t)row * DD + lane * 4] = pk;
    } else {
        int qb = DO_T ? (b - TBLOCKS) : b;
        int row = qb * 4 + wid;                     // covers exactly BQ rows
        uint2 pk = norm_row(q + (size_t)row * DD, lane);
        *(uint2*)&qn[(size_t)row * DD + lane * 4] = pk;
    }
}

// Stage one 64-row t-tile into LDS with XOR-swizzled 16B chunks.
// LDS slot (row, kb) holds global chunk (row, kb ^ (row&7)); reads invert the XOR.
// 8 waves: wave w stages rows [w*8, w*8+8) -> 4 gl_lds16 per wave.
template<bool PRE>
__device__ __forceinline__ void stage_tile(const unsigned short* __restrict__ tn,
                                           const float* __restrict__ t_raw,
                                           unsigned short* t_lds, int ti, int w, int lane) {
    if (PRE) {
        const unsigned short* tile = tn + (size_t)ti * 64 * DD;
        int rp = lane >> 5;        // row within pair
        int kb = lane & 31;        // 16B chunk within row
        #pragma unroll
        for (int i = 0; i < 4; ++i) {
            int row = w * 8 + i * 2 + rp;
            const unsigned short* src = tile + row * DD + ((kb ^ (row & 7)) << 3);
            gl_lds16(src, &t_lds[(w * 8 + i * 2) * DD]);
        }
    } else {
        // fallback: fused normalize from fp32 (ws too small for tn)
        int n0 = ti * 64;
        for (int i = 0; i < 8; ++i) {
            int row = w * 8 + i;
            int n = n0 + row;
            float4 v = make_float4(0.f, 0.f, 0.f, 0.f);
            if (n < NT) v = ((const float4*)t_raw)[(size_t)n * 64 + lane];
            float s = v.x * v.x + v.y * v.y + v.z * v.z + v.w * v.w;
            #pragma unroll
            for (int m = 1; m < 64; m <<= 1) s += __shfl_xor(s, m, 64);
            float sc = rsqrtf(fmaxf(s, 1e-24f));
            uint2 pk;
            pk.x = (unsigned)f2bf(v.x * sc) | ((unsigned)f2bf(v.y * sc) << 16);
            pk.y = (unsigned)f2bf(v.z * sc) | ((unsigned)f2bf(v.w * sc) << 16);
            int kb16 = lane >> 1, half = lane & 1;
            *(uint2*)&t_lds[row * DD + (((kb16 ^ (row & 7)) << 3) + (half << 2))] = pk;
        }
    }
}

// ---- main: A = t-tile (n rows), B = q (m cols); D row->n, col->m ----
// 512 threads = 8 waves in a 4m x 2n grid; block tile 128 m x 64 n.
// Each wave: 32 m (mi=2) x 32 n (ni=2); reads only its 16 KB n-half of the tile.
// KEY CHANGE (r10/r11): 2-deep accumulator pipeline. r9 showed no pipe >56%
// busy (matrix 28%, LDS 46%, HBM 11%) -> phase-boxed: MFMA phase and epilogue
// phase (32 sqrt+exp trans ops) serialize per iter. Now the epilogue of tile
// k-1 is placed INSIDE tile k's MFMA window (disjoint registers -> scheduler
// interleaves trans/VALU into MFMA shadow). Static accA/accB naming with a
// wave-uniform parity branch (no runtime indexing -> no scratch, rule #20).
// In-loop prev-epilogues are always FULL tiles (only tile 1562 is ragged and
// it is only ever drained post-loop). Drain handles full/masked.
// 2 x 32 KB double-buffered LDS -> 2 blocks/CU -> 4 waves/SIMD.
// XCD-grouped decode: g = blockIdx & 127 -> all 8 m-siblings on the same XCD.
// Counted vmcnt: each wave's 4 prefetch DMAs stay in flight across barriers.
template<bool PRE>
__global__ __launch_bounds__(512, 4) void knn_main(const unsigned short* __restrict__ tn,
                                                   const float* __restrict__ t_raw,
                                                   const unsigned short* __restrict__ qn,
                                                   float* __restrict__ acc_e,
                                                   float* __restrict__ acc_ed) {
    __shared__ unsigned short t_lds[2][64 * DD];   // 2 x 32 KB

    const int tid = threadIdx.x;
    const int lane = tid & 63, w = tid >> 6;       // w in 0..7
    const int wr = w >> 1;                         // m-subtile 0..3
    const int wc = w & 1;                          // n-half 0..1
    const int quad = lane >> 4, l16 = lane & 15;
    const int swz = l16 & 7;

    const int g = blockIdx.x & (NGROUPS - 1);   // n-group (siblings share t tiles)
    const int mchunk = blockIdx.x >> 7;         // log2(NGROUPS) == 7
    const int mbase = mchunk * 128;

    // q fragments: 32 q-rows per wave (2 x 16), 8 ksteps (64 VGPR if resident)
    bf16x8 qf[2][8];
    #pragma unroll
    for (int mi = 0; mi < 2; ++mi) {
        const unsigned short* qrow =
            qn + (size_t)(mbase + wr * 32 + mi * 16 + l16) * DD + quad * 8;
        #pragma unroll
        for (int ks = 0; ks < 8; ++ks)
            qf[mi][ks] = *(const bf16x8*)(qrow + ks * 32);
    }
    #pragma unroll
    for (int mi = 0; mi < 2; ++mi)
        #pragma unroll
        for (int ks = 0; ks < 8; ++ks)
            asm volatile("" : "+v"(qf[mi][ks]));

    float se0 = 0.f, se1 = 0.f, sd0 = 0.f, sd1 = 0.f;

    f32x4 accA[2][2], accB[2][2];   // [ni][mi], two statically-named sets

    // MFMA one tile from buf into the given acc set (zero-inits acc)
    auto mfma_block = [&](f32x4 (&acc)[2][2], const unsigned short* buf) {
        #pragma unroll
        for (int ni = 0; ni < 2; ++ni)
            #pragma unroll
            for (int mi = 0; mi < 2; ++mi)
                acc[ni][mi] = (f32x4){0.f, 0.f, 0.f, 0.f};
        #pragma unroll
        for (int ks = 0; ks < 8; ++ks) {
            bf16x8 a[2];
            #pragma unroll
            for (int ni = 0; ni < 2; ++ni)
                a[ni] = *(const bf16x8*)
                    &buf[(wc * 32 + ni * 16 + l16) * DD + (((ks * 4 + quad) ^ swz) << 3)];
            #pragma unroll
            for (int ni = 0; ni < 2; ++ni)
                #pragma unroll
                for (int mi = 0; mi < 2; ++mi)
                    acc[ni][mi] = __builtin_amdgcn_mfma_f32_16x16x32_bf16(
                        a[ni], qf[mi][ks], acc[ni][mi], 0, 0, 0);
        }
    };

    // full-tile epilogue (no bounds check — valid for every in-loop prev tile)
    auto epi_full = [&](const f32x4 (&acc)[2][2]) {
        #pragma unroll
        for (int ni = 0; ni < 2; ++ni)
            #pragma unroll
            for (int mi = 0; mi < 2; ++mi)
                #pragma unroll
                for (int r = 0; r < 4; ++r) {
                    float dot = acc[ni][mi][r];
                    float s = fmaf(-2.f, dot, 2.f);
                    float d = __builtin_amdgcn_sqrtf(fmaxf(s, 0.f));
                    float e = exp2f(-14.4269504089f * d);   // exp(-10d)
                    if (mi == 0) { se0 += e; sd0 = fmaf(e, d, sd0); }
                    else         { se1 += e; sd1 = fmaf(e, d, sd1); }
                }
    };

    // masked epilogue for the ragged final tile (n0 + 64 > NT)
    auto epi_masked = [&](const f32x4 (&acc)[2][2], int n0) {
        const int nq = n0 + wc * 32 + quad * 4;
        #pragma unroll
        for (int ni = 0; ni < 2; ++ni)
            #pragma unroll
            for (int mi = 0; mi < 2; ++mi)
                #pragma unroll
                for (int r = 0; r < 4; ++r) {
                    float dot = acc[ni][mi][r];
                    float s = fmaf(-2.f, dot, 2.f);
                    float d = __builtin_amdgcn_sqrtf(fmaxf(s, 0.f));
                    float e = (nq + ni * 16 + r < NT) ? exp2f(-14.4269504089f * d) : 0.f;
                    if (mi == 0) { se0 += e; sd0 = fmaf(e, d, sd0); }
                    else         { se1 += e; sd1 = fmaf(e, d, sd1); }
                }
    };

    // prologue: stage first two tiles (every group has >= 12 tiles)
    stage_tile<PRE>(tn, t_raw, t_lds[0], g, w, lane);
    stage_tile<PRE>(tn, t_raw, t_lds[1], g + NGROUPS, w, lane);

    int it = 0;
    int last_ti = g;
    for (int ti = g; ti < NTILES; ti += NGROUPS, ++it) {
        const unsigned short* buf = t_lds[it & 1];

        if constexpr (PRE) {
            // wait for MY tile's 4 DMA loads; leave the newer prefetch in flight
            if (ti + NGROUPS < NTILES)
                asm volatile("s_waitcnt vmcnt(4)" ::: "memory");
            else
                asm volatile("s_waitcnt vmcnt(0)" ::: "memory");
            __builtin_amdgcn_s_barrier();
            asm volatile("" ::: "memory");
        } else {
            __syncthreads();
        }

        // MFMA of tile `it` interleaved (by the scheduler) with the epilogue of
        // tile `it-1` — disjoint registers, separate pipes (matrix vs VALU/trans).
        if ((it & 1) == 0) {
            mfma_block(accA, buf);
            if (it > 0) epi_full(accB);
        } else {
            mfma_block(accB, buf);
            epi_full(accA);
        }

        if constexpr (PRE) {
            asm volatile("s_waitcnt lgkmcnt(0)" ::: "memory");  // my LDS reads done
            __builtin_amdgcn_s_barrier();                        // everyone done with buf
            asm volatile("" ::: "memory");
        } else {
            __syncthreads();
        }

        // prefetch tile t+2 into the buffer we just finished reading
        if (ti + 2 * NGROUPS < NTILES)
            stage_tile<PRE>(tn, t_raw, (unsigned short*)t_lds[it & 1],
                            ti + 2 * NGROUPS, w, lane);

        last_ti = ti;
    }

    // drain: epilogue of the final tile (parity (it-1)&1), full or masked
    {
        const int n0 = last_ti * 64;
        const bool full = (n0 + 64 <= NT);
        if (((it - 1) & 1) == 0) {
            if (full) epi_full(accA); else epi_masked(accA, n0);
        } else {
            if (full) epi_full(accB); else epi_masked(accB, n0);
        }
    }

    // reduce across quads (rows of D) — once per kernel, not per tile
    #pragma unroll
    for (int m = 16; m <= 32; m <<= 1) {
        se0 += __shfl_xor(se0, m, 64);
        se1 += __shfl_xor(se1, m, 64);
        sd0 += __shfl_xor(sd0, m, 64);
        sd1 += __shfl_xor(sd1, m, 64);
    }

    if (quad == 0) {
        int m0 = mbase + wr * 32 + l16;
        atomicAdd(&acc_e[m0],       se0);
        atomicAdd(&acc_e[m0 + 16],  se1);
        atomicAdd(&acc_ed[m0],      sd0);
        atomicAdd(&acc_ed[m0 + 16], sd1);
    }
}

__global__ void finalize(const float* __restrict__ acc_e, const float* __restrict__ acc_ed,
                         float* __restrict__ out) {
    int i = blockIdx.x * 256 + threadIdx.x;
    out[i] = acc_ed[i] / acc_e[i];
}

extern "C" void kernel_launch(void* const* d_in, const int* in_sizes, int n_in,
                              void* d_out, int out_size, void* d_ws, size_t ws_size,
                              hipStream_t stream) {
    const float* q = (const float*)d_in[0];   // [1024,256] fp32
    const float* t = (const float*)d_in[1];   // [100000,256] fp32
    float* out = (float*)d_out;               // [1024] fp32

    char* ws = (char*)d_ws;
    float* acc_e = (float*)ws;                               // 4 KB
    float* acc_ed = acc_e + BQ;                              // 4 KB
    unsigned short* qn = (unsigned short*)(ws + 8192);       // 512 KB
    unsigned short* tn = (unsigned short*)(ws + 8192 + (size_t)BQ * DD * 2);  // 51.2 MB

    size_t needed = 8192 + (size_t)BQ * DD * 2 + (size_t)NT_PAD * DD * 2;

    if (ws_size >= needed) {
        normalize_all<true><<<TBLOCKS + BQ / 4, 256, 0, stream>>>(q, t, qn, tn, acc_e);
        knn_main<true><<<NGROUPS * 8, 512, 0, stream>>>(tn, t, qn, acc_e, acc_ed);
    } else {
        normalize_all<false><<<BQ / 4, 256, 0, stream>>>(q, t, qn, tn, acc_e);
        knn_main<false><<<NGROUPS * 8, 512, 0, stream>>>(tn, t, qn, acc_e, acc_ed);
    }
    finalize<<<BQ / 256, 256, 0, stream>>>(acc_e, acc_ed, out);
}

// Round 12
// 350.463 us; speedup vs baseline: 2.0677x; 2.0677x over previous
//
#include <hip/hip_runtime.h>
#include <hip/hip_bf16.h>

#define NT 100000
#define NT_PAD 100032     // 1563 * 64
#define BQ 1024
#define DD 256
#define NGROUPS 128
#define NTILES 1563       // ceil(100000/64)
#define TBLOCKS (NT_PAD / 4)   // 25008 blocks for t rows in normalize_all

typedef __attribute__((ext_vector_type(8))) short bf16x8;
typedef __attribute__((ext_vector_type(4))) float f32x4;

__device__ __forceinline__ unsigned short f2bf(float x) {
    union { float f; unsigned u; } a; a.f = x;
    unsigned r = (a.u + 0x7fffu + ((a.u >> 16) & 1u)) >> 16;  // RNE
    return (unsigned short)r;
}

// ---- normalize one fp32 row (256 elems) -> packed bf16 uint2 for this lane ----
__device__ __forceinline__ uint2 norm_row(const float* __restrict__ src, int lane) {
    float4 v = ((const float4*)src)[lane];
    float s = v.x * v.x + v.y * v.y + v.z * v.z + v.w * v.w;
    #pragma unroll
    for (int m = 1; m < 64; m <<= 1) s += __shfl_xor(s, m, 64);
    float sc = rsqrtf(fmaxf(s, 1e-24f));
    uint2 pk;
    pk.x = (unsigned)f2bf(v.x * sc) | ((unsigned)f2bf(v.y * sc) << 16);
    pk.y = (unsigned)f2bf(v.z * sc) | ((unsigned)f2bf(v.w * sc) << 16);
    return pk;
}

// ---- fused: zero accumulators + normalize q + (optionally) normalize t ----
template<bool DO_T>
__global__ void normalize_all(const float* __restrict__ q, const float* __restrict__ t,
                              unsigned short* __restrict__ qn, unsigned short* __restrict__ tn,
                              float* __restrict__ accz) {
    int lane = threadIdx.x & 63, wid = threadIdx.x >> 6;
    int b = blockIdx.x;
    if (b < 8) accz[b * 256 + threadIdx.x] = 0.f;   // acc_e(1024) + acc_ed(1024)

    if (DO_T && b < TBLOCKS) {
        int row = b * 4 + wid;                      // covers exactly NT_PAD rows
        uint2 pk; pk.x = 0u; pk.y = 0u;
        if (row < NT) pk = norm_row(t + (size_t)row * DD, lane);
        *(uint2*)&tn[(size_t)row * DD + lane * 4] = pk;
    } else {
        int qb = DO_T ? (b - TBLOCKS) : b;
        int row = qb * 4 + wid;                     // covers exactly BQ rows
        uint2 pk = norm_row(q + (size_t)row * DD, lane);
        *(uint2*)&qn[(size_t)row * DD + lane * 4] = pk;
    }
}

// ================= PRIMARY PATH: direct-from-L2, no LDS =================
// r11 post-mortem: acc-pipeline via lambdas spilled to scratch (WRITE_SIZE
// 2MB->1.13GB, 7x regression) — reverted. r9's measured profile showed no pipe
// >56% (matrix 28%, LDS 46%+conflicts, HBM 11%) and q-fragments never
// register-resident (VGPR=64 in every config): the barrier/clobber-laced LDS
// staging loop itself was the tax. This kernel DELETES the LDS machinery:
//  - tn tiles are L2-resident per XCD (XCD-grouped decode: g = blockIdx&127,
//    so all 8 m-siblings of a group live on one XCD; live set ~1 MB << 4 MB).
//  - A-fragments load directly global->VGPR: lanes (l16, quad=0..3) read 64 B
//    contiguous; 16 dwordx4 loads per wave-iter.
//  - NO barriers / vmcnt asm / memory clobbers in the loop -> waves fully
//    independent; scheduler pipelines loads under MFMA; loop-invariant q
//    loads can finally be hoisted and stay resident (qf 64 VGPR).
// Wave = 32 q-rows (mi=2) x 32 t-rows (ni=2); block 128q x 64t per iter.
__global__ __launch_bounds__(512, 4) void knn_direct(const unsigned short* __restrict__ tn,
                                                     const unsigned short* __restrict__ qn,
                                                     float* __restrict__ acc_e,
                                                     float* __restrict__ acc_ed) {
    const int tid = threadIdx.x;
    const int lane = tid & 63, w = tid >> 6;       // w in 0..7
    const int wr = w >> 1;                         // m-subtile 0..3
    const int wc = w & 1;                          // n-half 0..1
    const int quad = lane >> 4, l16 = lane & 15;

    const int g = blockIdx.x & (NGROUPS - 1);   // n-group (siblings share t tiles)
    const int mchunk = blockIdx.x >> 7;         // log2(NGROUPS) == 7
    const int mbase = mchunk * 128;

    // q fragments: 32 q-rows per wave (2 x 16), 8 ksteps — 64 VGPR resident
    bf16x8 qf[2][8];
    #pragma unroll
    for (int mi = 0; mi < 2; ++mi) {
        const unsigned short* qrow =
            qn + (size_t)(mbase + wr * 32 + mi * 16 + l16) * DD + quad * 8;
        #pragma unroll
        for (int ks = 0; ks < 8; ++ks)
            qf[mi][ks] = *(const bf16x8*)(qrow + ks * 32);
    }
    #pragma unroll
    for (int mi = 0; mi < 2; ++mi)
        #pragma unroll
        for (int ks = 0; ks < 8; ++ks)
            asm volatile("" : "+v"(qf[mi][ks]));

    float se0 = 0.f, se1 = 0.f, sd0 = 0.f, sd1 = 0.f;

    // per-lane base into a tile: row = wc*32 + l16 (+ni*16), col = quad*8 (+ks*32)
    const unsigned short* tbase = tn + (size_t)(wc * 32 + l16) * DD + quad * 8
                                     + (size_t)g * 64 * DD;
    const size_t tile_step = (size_t)NGROUPS * 64 * DD;

    for (int ti = g; ti < NTILES; ti += NGROUPS, tbase += tile_step) {
        f32x4 acc[2][2];   // [ni][mi]
        #pragma unroll
        for (int ni = 0; ni < 2; ++ni)
            #pragma unroll
            for (int mi = 0; mi < 2; ++mi)
                acc[ni][mi] = (f32x4){0.f, 0.f, 0.f, 0.f};

        #pragma unroll
        for (int ks = 0; ks < 8; ++ks) {
            bf16x8 a[2];
            #pragma unroll
            for (int ni = 0; ni < 2; ++ni)
                a[ni] = *(const bf16x8*)(tbase + ni * 16 * DD + ks * 32);
            #pragma unroll
            for (int ni = 0; ni < 2; ++ni)
                #pragma unroll
                for (int mi = 0; mi < 2; ++mi)
                    acc[ni][mi] = __builtin_amdgcn_mfma_f32_16x16x32_bf16(
                        a[ni], qf[mi][ks], acc[ni][mi], 0, 0, 0);
        }

        // inline epilogue (r9 structure — measured good)
        const int n0 = ti * 64;
        if (n0 + 64 <= NT) {
            #pragma unroll
            for (int ni = 0; ni < 2; ++ni)
                #pragma unroll
                for (int mi = 0; mi < 2; ++mi)
                    #pragma unroll
                    for (int r = 0; r < 4; ++r) {
                        float dot = acc[ni][mi][r];
                        float s = fmaf(-2.f, dot, 2.f);
                        float d = __builtin_amdgcn_sqrtf(fmaxf(s, 0.f));
                        float e = exp2f(-14.4269504089f * d);   // exp(-10d)
                        if (mi == 0) { se0 += e; sd0 = fmaf(e, d, sd0); }
                        else         { se1 += e; sd1 = fmaf(e, d, sd1); }
                    }
        } else {
            const int nq = n0 + wc * 32 + quad * 4;
            #pragma unroll
            for (int ni = 0; ni < 2; ++ni)
                #pragma unroll
                for (int mi = 0; mi < 2; ++mi)
                    #pragma unroll
                    for (int r = 0; r < 4; ++r) {
                        float dot = acc[ni][mi][r];
                        float s = fmaf(-2.f, dot, 2.f);
                        float d = __builtin_amdgcn_sqrtf(fmaxf(s, 0.f));
                        float e = (nq + ni * 16 + r < NT) ? exp2f(-14.4269504089f * d) : 0.f;
                        if (mi == 0) { se0 += e; sd0 = fmaf(e, d, sd0); }
                        else         { se1 += e; sd1 = fmaf(e, d, sd1); }
                    }
        }
    }

    // reduce across quads (rows of D) — once per kernel
    #pragma unroll
    for (int m = 16; m <= 32; m <<= 1) {
        se0 += __shfl_xor(se0, m, 64);
        se1 += __shfl_xor(se1, m, 64);
        sd0 += __shfl_xor(sd0, m, 64);
        sd1 += __shfl_xor(sd1, m, 64);
    }

    if (quad == 0) {
        int m0 = mbase + wr * 32 + l16;
        atomicAdd(&acc_e[m0],       se0);
        atomicAdd(&acc_e[m0 + 16],  se1);
        atomicAdd(&acc_ed[m0],      sd0);
        atomicAdd(&acc_ed[m0 + 16], sd1);
    }
}

// ================= FALLBACK PATH (ws too small): r9 LDS kernel =================
__global__ __launch_bounds__(512, 4) void knn_fallback(const float* __restrict__ t_raw,
                                                       const unsigned short* __restrict__ qn,
                                                       float* __restrict__ acc_e,
                                                       float* __restrict__ acc_ed) {
    __shared__ unsigned short t_lds[2][64 * DD];   // 2 x 32 KB

    const int tid = threadIdx.x;
    const int lane = tid & 63, w = tid >> 6;
    const int wr = w >> 1, wc = w & 1;
    const int quad = lane >> 4, l16 = lane & 15;
    const int swz = l16 & 7;

    const int g = blockIdx.x & (NGROUPS - 1);
    const int mchunk = blockIdx.x >> 7;
    const int mbase = mchunk * 128;

    bf16x8 qf[2][8];
    #pragma unroll
    for (int mi = 0; mi < 2; ++mi) {
        const unsigned short* qrow =
            qn + (size_t)(mbase + wr * 32 + mi * 16 + l16) * DD + quad * 8;
        #pragma unroll
        for (int ks = 0; ks < 8; ++ks)
            qf[mi][ks] = *(const bf16x8*)(qrow + ks * 32);
    }

    auto stage = [&](unsigned short* dst, int ti) {
        int n0 = ti * 64;
        for (int i = 0; i < 8; ++i) {
            int row = w * 8 + i;
            int n = n0 + row;
            float4 v = make_float4(0.f, 0.f, 0.f, 0.f);
            if (n < NT) v = ((const float4*)t_raw)[(size_t)n * 64 + lane];
            float s = v.x * v.x + v.y * v.y + v.z * v.z + v.w * v.w;
            #pragma unroll
            for (int m = 1; m < 64; m <<= 1) s += __shfl_xor(s, m, 64);
            float sc = rsqrtf(fmaxf(s, 1e-24f));
            uint2 pk;
            pk.x = (unsigned)f2bf(v.x * sc) | ((unsigned)f2bf(v.y * sc) << 16);
            pk.y = (unsigned)f2bf(v.z * sc) | ((unsigned)f2bf(v.w * sc) << 16);
            int kb16 = lane >> 1, half = lane & 1;
            *(uint2*)&dst[row * DD + (((kb16 ^ (row & 7)) << 3) + (half << 2))] = pk;
        }
    };

    float se0 = 0.f, se1 = 0.f, sd0 = 0.f, sd1 = 0.f;

    stage(t_lds[0], g);
    if (g + NGROUPS < NTILES) stage(t_lds[1], g + NGROUPS);

    int it = 0;
    for (int ti = g; ti < NTILES; ti += NGROUPS, ++it) {
        const unsigned short* buf = t_lds[it & 1];
        __syncthreads();

        f32x4 acc[2][2];
        #pragma unroll
        for (int ni = 0; ni < 2; ++ni)
            #pragma unroll
            for (int mi = 0; mi < 2; ++mi)
                acc[ni][mi] = (f32x4){0.f, 0.f, 0.f, 0.f};

        #pragma unroll
        for (int ks = 0; ks < 8; ++ks) {
            bf16x8 a[2];
            #pragma unroll
            for (int ni = 0; ni < 2; ++ni)
                a[ni] = *(const bf16x8*)
                    &buf[(wc * 32 + ni * 16 + l16) * DD + (((ks * 4 + quad) ^ swz) << 3)];
            #pragma unroll
            for (int ni = 0; ni < 2; ++ni)
                #pragma unroll
                for (int mi = 0; mi < 2; ++mi)
                    acc[ni][mi] = __builtin_amdgcn_mfma_f32_16x16x32_bf16(
                        a[ni], qf[mi][ks], acc[ni][mi], 0, 0, 0);
        }

        __syncthreads();
        if (ti + 2 * NGROUPS < NTILES) stage((unsigned short*)t_lds[it & 1], ti + 2 * NGROUPS);

        const int n0 = ti * 64;
        if (n0 + 64 <= NT) {
            #pragma unroll
            for (int ni = 0; ni < 2; ++ni)
                #pragma unroll
                for (int mi = 0; mi < 2; ++mi)
                    #pragma unroll
                    for (int r = 0; r < 4; ++r) {
                        float dot = acc[ni][mi][r];
                        float s = fmaf(-2.f, dot, 2.f);
                        float d = __builtin_amdgcn_sqrtf(fmaxf(s, 0.f));
                        float e = exp2f(-14.4269504089f * d);
                        if (mi == 0) { se0 += e; sd0 = fmaf(e, d, sd0); }
                        else         { se1 += e; sd1 = fmaf(e, d, sd1); }
                    }
        } else {
            const int nq = n0 + wc * 32 + quad * 4;
            #pragma unroll
            for (int ni = 0; ni < 2; ++ni)
                #pragma unroll
                for (int mi = 0; mi < 2; ++mi)
                    #pragma unroll
                    for (int r = 0; r < 4; ++r) {
                        float dot = acc[ni][mi][r];
                        float s = fmaf(-2.f, dot, 2.f);
                        float d = __builtin_amdgcn_sqrtf(fmaxf(s, 0.f));
                        float e = (nq + ni * 16 + r < NT) ? exp2f(-14.4269504089f * d) : 0.f;
                        if (mi == 0) { se0 += e; sd0 = fmaf(e, d, sd0); }
                        else         { se1 += e; sd1 = fmaf(e, d, sd1); }
                    }
        }
    }

    #pragma unroll
    for (int m = 16; m <= 32; m <<= 1) {
        se0 += __shfl_xor(se0, m, 64);
        se1 += __shfl_xor(se1, m, 64);
        sd0 += __shfl_xor(sd0, m, 64);
        sd1 += __shfl_xor(sd1, m, 64);
    }

    if (quad == 0) {
        int m0 = mbase + wr * 32 + l16;
        atomicAdd(&acc_e[m0],       se0);
        atomicAdd(&acc_e[m0 + 16],  se1);
        atomicAdd(&acc_ed[m0],      sd0);
        atomicAdd(&acc_ed[m0 + 16], sd1);
    }
}

__global__ void finalize(const float* __restrict__ acc_e, const float* __restrict__ acc_ed,
                         float* __restrict__ out) {
    int i = blockIdx.x * 256 + threadIdx.x;
    out[i] = acc_ed[i] / acc_e[i];
}

extern "C" void kernel_launch(void* const* d_in, const int* in_sizes, int n_in,
                              void* d_out, int out_size, void* d_ws, size_t ws_size,
                              hipStream_t stream) {
    const float* q = (const float*)d_in[0];   // [1024,256] fp32
    const float* t = (const float*)d_in[1];   // [100000,256] fp32
    float* out = (float*)d_out;               // [1024] fp32

    char* ws = (char*)d_ws;
    float* acc_e = (float*)ws;                               // 4 KB
    float* acc_ed = acc_e + BQ;                              // 4 KB
    unsigned short* qn = (unsigned short*)(ws + 8192);       // 512 KB
    unsigned short* tn = (unsigned short*)(ws + 8192 + (size_t)BQ * DD * 2);  // 51.2 MB

    size_t needed = 8192 + (size_t)BQ * DD * 2 + (size_t)NT_PAD * DD * 2;

    if (ws_size >= needed) {
        normalize_all<true><<<TBLOCKS + BQ / 4, 256, 0, stream>>>(q, t, qn, tn, acc_e);
        knn_direct<<<NGROUPS * 8, 512, 0, stream>>>(tn, qn, acc_e, acc_ed);
    } else {
        normalize_all<false><<<BQ / 4, 256, 0, stream>>>(q, t, qn, tn, acc_e);
        knn_fallback<<<NGROUPS * 8, 512, 0, stream>>>(t, qn, acc_e, acc_ed);
    }
    finalize<<<BQ / 256, 256, 0, stream>>>(acc_e, acc_ed, out);
}

// Round 14
// 233.268 us; speedup vs baseline: 3.1066x; 1.5024x over previous
//
#include <hip/hip_runtime.h>
#include <hip/hip_bf16.h>

#define NT 100000
#define NT_PAD 100032     // 1563 * 64
#define BQ 1024
#define DD 256
#define NGROUPS 128
#define NTILES 1563       // ceil(100000/64)
#define TBLOCKS (NT_PAD / 4)   // 25008 blocks for t rows in normalize_all

typedef __attribute__((ext_vector_type(8))) short bf16x8;
typedef __attribute__((ext_vector_type(4))) float f32x4;

__device__ __forceinline__ unsigned short f2bf(float x) {
    union { float f; unsigned u; } a; a.f = x;
    unsigned r = (a.u + 0x7fffu + ((a.u >> 16) & 1u)) >> 16;  // RNE
    return (unsigned short)r;
}

// async global->LDS DMA, 16B per lane; lds dest must be wave-uniform base
__device__ __forceinline__ void gl_lds16(const void* g, void* l) {
    __builtin_amdgcn_global_load_lds(
        (const __attribute__((address_space(1))) unsigned int*)g,
        (__attribute__((address_space(3))) unsigned int*)l, 16, 0, 0);
}

// ---- normalize one fp32 row (256 elems) -> packed bf16 uint2 for this lane ----
__device__ __forceinline__ uint2 norm_row(const float* __restrict__ src, int lane) {
    float4 v = ((const float4*)src)[lane];
    float s = v.x * v.x + v.y * v.y + v.z * v.z + v.w * v.w;
    #pragma unroll
    for (int m = 1; m < 64; m <<= 1) s += __shfl_xor(s, m, 64);
    float sc = rsqrtf(fmaxf(s, 1e-24f));
    uint2 pk;
    pk.x = (unsigned)f2bf(v.x * sc) | ((unsigned)f2bf(v.y * sc) << 16);
    pk.y = (unsigned)f2bf(v.z * sc) | ((unsigned)f2bf(v.w * sc) << 16);
    return pk;
}

// ---- fused: zero accumulators + normalize q + (optionally) normalize t ----
template<bool DO_T>
__global__ void normalize_all(const float* __restrict__ q, const float* __restrict__ t,
                              unsigned short* __restrict__ qn, unsigned short* __restrict__ tn,
                              float* __restrict__ accz) {
    int lane = threadIdx.x & 63, wid = threadIdx.x >> 6;
    int b = blockIdx.x;
    if (b < 8) accz[b * 256 + threadIdx.x] = 0.f;   // acc_e(1024) + acc_ed(1024)

    if (DO_T && b < TBLOCKS) {
        int row = b * 4 + wid;                      // covers exactly NT_PAD rows
        uint2 pk; pk.x = 0u; pk.y = 0u;
        if (row < NT) pk = norm_row(t + (size_t)row * DD, lane);
        *(uint2*)&tn[(size_t)row * DD + lane * 4] = pk;
    } else {
        int qb = DO_T ? (b - TBLOCKS) : b;
        int row = qb * 4 + wid;                     // covers exactly BQ rows
        uint2 pk = norm_row(q + (size_t)row * DD, lane);
        *(uint2*)&qn[(size_t)row * DD + lane * 4] = pk;
    }
}

// Stage one 64-row t-tile into LDS with XOR-swizzled 16B chunks.
// LDS slot (row, kb) holds global chunk (row, kb ^ (row&7)); reads invert the XOR.
// 8 waves: wave w stages rows [w*8, w*8+8) -> 4 gl_lds16 per wave.
template<bool PRE>
__device__ __forceinline__ void stage_tile(const unsigned short* __restrict__ tn,
                                           const float* __restrict__ t_raw,
                                           unsigned short* t_lds, int ti, int w, int lane) {
    if (PRE) {
        const unsigned short* tile = tn + (size_t)ti * 64 * DD;
        int rp = lane >> 5;        // row within pair
        int kb = lane & 31;        // 16B chunk within row
        #pragma unroll
        for (int i = 0; i < 4; ++i) {
            int row = w * 8 + i * 2 + rp;
            const unsigned short* src = tile + row * DD + ((kb ^ (row & 7)) << 3);
            gl_lds16(src, &t_lds[(w * 8 + i * 2) * DD]);
        }
    } else {
        // fallback: fused normalize from fp32 (ws too small for tn)
        int n0 = ti * 64;
        for (int i = 0; i < 8; ++i) {
            int row = w * 8 + i;
            int n = n0 + row;
            float4 v = make_float4(0.f, 0.f, 0.f, 0.f);
            if (n < NT) v = ((const float4*)t_raw)[(size_t)n * 64 + lane];
            float s = v.x * v.x + v.y * v.y + v.z * v.z + v.w * v.w;
            #pragma unroll
            for (int m = 1; m < 64; m <<= 1) s += __shfl_xor(s, m, 64);
            float sc = rsqrtf(fmaxf(s, 1e-24f));
            uint2 pk;
            pk.x = (unsigned)f2bf(v.x * sc) | ((unsigned)f2bf(v.y * sc) << 16);
            pk.y = (unsigned)f2bf(v.z * sc) | ((unsigned)f2bf(v.w * sc) << 16);
            int kb16 = lane >> 1, half = lane & 1;
            *(uint2*)&t_lds[row * DD + (((kb16 ^ (row & 7)) << 3) + (half << 2))] = pk;
        }
    }
}

// ---- main: A = t-tile (n rows), B = q (m cols); D row->n, col->m ----
// 512 threads = 8 waves in a 4m x 2n grid; block tile 128 m x 64 n.
// Each wave: 32 m (mi=2) x 32 n (ni=2); reads only its 16 KB n-half of the tile.
// KEY CHANGE (r13/r14): amdgpu_waves_per_eu(4,4) replaces __launch_bounds__(512,4).
// Unifying theory for VGPR pinned at <=64 across ALL measured rounds
// (88/52/64/64/64/60): launch_bounds' 2nd arg only sets MIN waves/EU; LLVM's
// RA budgets registers for the range MAX (8 waves/EU -> 64 VGPR) and under
// that cap rematerializes/reloads the invariant qf loads every tile-iter
// (seen as FETCH 75 MB vs 52 ideal, ~100 extra VALU/iter, VALUBusy 56%).
// Our 64 KB LDS already caps occupancy at 2 blocks/CU = 4 waves/SIMD, so the
// 64-VGPR budget buys NOTHING. Pinning waves-per-eu to [4,4] gives the RA a
// 128-VGPR budget: qf(64) + acc(16) + temps ~= 110 fits without remat.
// GATE: VGPR_Count must rise to >=96; if it stays 64 the theory is refuted.
// 2 x 32 KB double-buffered LDS; XCD-grouped decode (g = blockIdx & 127);
// counted vmcnt keeps each wave's 4 prefetch DMAs in flight across barriers.
template<bool PRE>
__global__ __launch_bounds__(512)
__attribute__((amdgpu_waves_per_eu(4, 4)))
void knn_main(const unsigned short* __restrict__ tn,
              const float* __restrict__ t_raw,
              const unsigned short* __restrict__ qn,
              float* __restrict__ acc_e,
              float* __restrict__ acc_ed) {
    __shared__ unsigned short t_lds[2][64 * DD];   // 2 x 32 KB

    const int tid = threadIdx.x;
    const int lane = tid & 63, w = tid >> 6;       // w in 0..7
    const int wr = w >> 1;                         // m-subtile 0..3
    const int wc = w & 1;                          // n-half 0..1
    const int quad = lane >> 4, l16 = lane & 15;
    const int swz = l16 & 7;

    const int g = blockIdx.x & (NGROUPS - 1);   // n-group (siblings share t tiles)
    const int mchunk = blockIdx.x >> 7;         // log2(NGROUPS) == 7
    const int mbase = mchunk * 128;

    // q fragments: 32 q-rows per wave (2 x 16), 8 ksteps — 64 VGPR resident
    bf16x8 qf[2][8];
    #pragma unroll
    for (int mi = 0; mi < 2; ++mi) {
        const unsigned short* qrow =
            qn + (size_t)(mbase + wr * 32 + mi * 16 + l16) * DD + quad * 8;
        #pragma unroll
        for (int ks = 0; ks < 8; ++ks)
            qf[mi][ks] = *(const bf16x8*)(qrow + ks * 32);
    }
    #pragma unroll
    for (int mi = 0; mi < 2; ++mi)
        #pragma unroll
        for (int ks = 0; ks < 8; ++ks)
            asm volatile("" : "+v"(qf[mi][ks]));

    float se0 = 0.f, se1 = 0.f, sd0 = 0.f, sd1 = 0.f;

    // prologue: stage first two tiles (every group has >= 12 tiles)
    stage_tile<PRE>(tn, t_raw, t_lds[0], g, w, lane);
    stage_tile<PRE>(tn, t_raw, t_lds[1], g + NGROUPS, w, lane);

    int it = 0;
    for (int ti = g; ti < NTILES; ti += NGROUPS, ++it) {
        const unsigned short* buf = t_lds[it & 1];

        if constexpr (PRE) {
            // wait for MY tile's 4 DMA loads; leave the newer prefetch in flight
            if (ti + NGROUPS < NTILES)
                asm volatile("s_waitcnt vmcnt(4)" ::: "memory");
            else
                asm volatile("s_waitcnt vmcnt(0)" ::: "memory");
            __builtin_amdgcn_s_barrier();
            asm volatile("" ::: "memory");
        } else {
            __syncthreads();
        }

        f32x4 acc[2][2];   // [ni][mi]
        #pragma unroll
        for (int ni = 0; ni < 2; ++ni)
            #pragma unroll
            for (int mi = 0; mi < 2; ++mi)
                acc[ni][mi] = (f32x4){0.f, 0.f, 0.f, 0.f};

        #pragma unroll
        for (int ks = 0; ks < 8; ++ks) {
            bf16x8 a[2];
            #pragma unroll
            for (int ni = 0; ni < 2; ++ni)
                a[ni] = *(const bf16x8*)
                    &buf[(wc * 32 + ni * 16 + l16) * DD + (((ks * 4 + quad) ^ swz) << 3)];
            #pragma unroll
            for (int ni = 0; ni < 2; ++ni)
                #pragma unroll
                for (int mi = 0; mi < 2; ++mi)
                    acc[ni][mi] = __builtin_amdgcn_mfma_f32_16x16x32_bf16(
                        a[ni], qf[mi][ks], acc[ni][mi], 0, 0, 0);
        }

        if constexpr (PRE) {
            asm volatile("s_waitcnt lgkmcnt(0)" ::: "memory");  // my LDS reads done
            __builtin_amdgcn_s_barrier();                        // everyone done with buf
            asm volatile("" ::: "memory");
        } else {
            __syncthreads();
        }

        // prefetch tile t+2 into the buffer we just finished reading
        if (ti + 2 * NGROUPS < NTILES)
            stage_tile<PRE>(tn, t_raw, (unsigned short*)t_lds[it & 1],
                            ti + 2 * NGROUPS, w, lane);

        // epilogue (registers only — overlaps the prefetch DMA; no shuffles)
        const int n0 = ti * 64;
        if (n0 + 64 <= NT) {
            #pragma unroll
            for (int ni = 0; ni < 2; ++ni)
                #pragma unroll
                for (int mi = 0; mi < 2; ++mi)
                    #pragma unroll
                    for (int r = 0; r < 4; ++r) {
                        float dot = acc[ni][mi][r];
                        float s = fmaf(-2.f, dot, 2.f);
                        float d = __builtin_amdgcn_sqrtf(fmaxf(s, 0.f));
                        float e = exp2f(-14.4269504089f * d);   // exp(-10d)
                        if (mi == 0) { se0 += e; sd0 = fmaf(e, d, sd0); }
                        else         { se1 += e; sd1 = fmaf(e, d, sd1); }
                    }
        } else {
            const int nq = n0 + wc * 32 + quad * 4;
            #pragma unroll
            for (int ni = 0; ni < 2; ++ni)
                #pragma unroll
                for (int mi = 0; mi < 2; ++mi)
                    #pragma unroll
                    for (int r = 0; r < 4; ++r) {
                        float dot = acc[ni][mi][r];
                        float s = fmaf(-2.f, dot, 2.f);
                        float d = __builtin_amdgcn_sqrtf(fmaxf(s, 0.f));
                        float e = (nq + ni * 16 + r < NT) ? exp2f(-14.4269504089f * d) : 0.f;
                        if (mi == 0) { se0 += e; sd0 = fmaf(e, d, sd0); }
                        else         { se1 += e; sd1 = fmaf(e, d, sd1); }
                    }
        }
    }

    // reduce across quads (rows of D) — once per kernel, not per tile
    #pragma unroll
    for (int m = 16; m <= 32; m <<= 1) {
        se0 += __shfl_xor(se0, m, 64);
        se1 += __shfl_xor(se1, m, 64);
        sd0 += __shfl_xor(sd0, m, 64);
        sd1 += __shfl_xor(sd1, m, 64);
    }

    if (quad == 0) {
        int m0 = mbase + wr * 32 + l16;
        atomicAdd(&acc_e[m0],       se0);
        atomicAdd(&acc_e[m0 + 16],  se1);
        atomicAdd(&acc_ed[m0],      sd0);
        atomicAdd(&acc_ed[m0 + 16], sd1);
    }
}

__global__ void finalize(const float* __restrict__ acc_e, const float* __restrict__ acc_ed,
                         float* __restrict__ out) {
    int i = blockIdx.x * 256 + threadIdx.x;
    out[i] = acc_ed[i] / acc_e[i];
}

extern "C" void kernel_launch(void* const* d_in, const int* in_sizes, int n_in,
                              void* d_out, int out_size, void* d_ws, size_t ws_size,
                              hipStream_t stream) {
    const float* q = (const float*)d_in[0];   // [1024,256] fp32
    const float* t = (const float*)d_in[1];   // [100000,256] fp32
    float* out = (float*)d_out;               // [1024] fp32

    char* ws = (char*)d_ws;
    float* acc_e = (float*)ws;                               // 4 KB
    float* acc_ed = acc_e + BQ;                              // 4 KB
    unsigned short* qn = (unsigned short*)(ws + 8192);       // 512 KB
    unsigned short* tn = (unsigned short*)(ws + 8192 + (size_t)BQ * DD * 2);  // 51.2 MB

    size_t needed = 8192 + (size_t)BQ * DD * 2 + (size_t)NT_PAD * DD * 2;

    if (ws_size >= needed) {
        normalize_all<true><<<TBLOCKS + BQ / 4, 256, 0, stream>>>(q, t, qn, tn, acc_e);
        knn_main<true><<<NGROUPS * 8, 512, 0, stream>>>(tn, t, qn, acc_e, acc_ed);
    } else {
        normalize_all<false><<<BQ / 4, 256, 0, stream>>>(q, t, qn, tn, acc_e);
        knn_main<false><<<NGROUPS * 8, 512, 0, stream>>>(tn, t, qn, acc_e, acc_ed);
    }
    finalize<<<BQ / 256, 256, 0, stream>>>(acc_e, acc_ed, out);
}